// Round 1
// baseline (1022.667 us; speedup 1.0000x reference)
//
#include <hip/hip_runtime.h>
#include <math.h>

#define BB 8
#define SS 4096
#define EE 128
#define HH 64
#define QR 64   // q rows per flash block
#define KT 32   // key tile

// ---------------- QKV projection ----------------
// grid: B*S/64 blocks, 192 threads. Block = 64 rows of x staged in LDS.
// Thread t owns one output column of {Q,K,V} (which = t/64) for all 64 rows.
// LDS reads are wave-uniform -> broadcast, conflict-free.
__global__ __launch_bounds__(192) void qkv_proj_kernel(
    const float* __restrict__ x,
    const float* __restrict__ Wq, const float* __restrict__ bq,
    const float* __restrict__ Wk, const float* __restrict__ bk,
    const float* __restrict__ Wv, const float* __restrict__ bv,
    float* __restrict__ Q, float* __restrict__ K, float* __restrict__ V)
{
    __shared__ float xs[64 * EE];
    const int tid = threadIdx.x;
    const long rowbase = (long)blockIdx.x * 64;

    const float4* xg = (const float4*)(x + rowbase * EE);
    float4* xs4 = (float4*)xs;
    for (int i = tid; i < 64 * EE / 4; i += 192) xs4[i] = xg[i];
    __syncthreads();

    const int col = tid & 63;
    const int which = tid >> 6;                 // wave-uniform (192 = 3 waves)
    const float* W    = (which == 0) ? Wq : (which == 1) ? Wk : Wv;
    const float* bias = (which == 0) ? bq : (which == 1) ? bk : bv;
    float* Out        = (which == 0) ? Q  : (which == 1) ? K  : V;

    float acc[64];
    const float b = bias[col];
#pragma unroll
    for (int r = 0; r < 64; ++r) acc[r] = b;

    for (int e = 0; e < EE; e += 4) {
        const float w0 = W[(e + 0) * HH + col];
        const float w1 = W[(e + 1) * HH + col];
        const float w2 = W[(e + 2) * HH + col];
        const float w3 = W[(e + 3) * HH + col];
#pragma unroll
        for (int r = 0; r < 64; ++r) {
            const float4 xv = *(const float4*)(xs + r * EE + e);
            float a = acc[r];
            a = fmaf(w0, xv.x, a);
            a = fmaf(w1, xv.y, a);
            a = fmaf(w2, xv.z, a);
            a = fmaf(w3, xv.w, a);
            acc[r] = a;
        }
    }
#pragma unroll
    for (int r = 0; r < 64; ++r) Out[(rowbase + r) * HH + col] = acc[r];
}

// ---------------- flash attention (fp32, online softmax) ----------------
__device__ __forceinline__ float dot16(const float4 a0, const float4 a1,
                                       const float4 a2, const float4 a3,
                                       const float* p) {
    const float4 b0 = ((const float4*)p)[0];
    const float4 b1 = ((const float4*)p)[1];
    const float4 b2 = ((const float4*)p)[2];
    const float4 b3 = ((const float4*)p)[3];
    float s = a0.x * b0.x;
    s = fmaf(a0.y, b0.y, s); s = fmaf(a0.z, b0.z, s); s = fmaf(a0.w, b0.w, s);
    s = fmaf(a1.x, b1.x, s); s = fmaf(a1.y, b1.y, s); s = fmaf(a1.z, b1.z, s); s = fmaf(a1.w, b1.w, s);
    s = fmaf(a2.x, b2.x, s); s = fmaf(a2.y, b2.y, s); s = fmaf(a2.z, b2.z, s); s = fmaf(a2.w, b2.w, s);
    s = fmaf(a3.x, b3.x, s); s = fmaf(a3.y, b3.y, s); s = fmaf(a3.z, b3.z, s); s = fmaf(a3.w, b3.w, s);
    return s;
}

__device__ __forceinline__ void pvacc(const float p, const float* vp, float* o) {
    const float4 v0 = ((const float4*)vp)[0];
    const float4 v1 = ((const float4*)vp)[1];
    const float4 v2 = ((const float4*)vp)[2];
    const float4 v3 = ((const float4*)vp)[3];
    o[0]  = fmaf(p, v0.x, o[0]);  o[1]  = fmaf(p, v0.y, o[1]);
    o[2]  = fmaf(p, v0.z, o[2]);  o[3]  = fmaf(p, v0.w, o[3]);
    o[4]  = fmaf(p, v1.x, o[4]);  o[5]  = fmaf(p, v1.y, o[5]);
    o[6]  = fmaf(p, v1.z, o[6]);  o[7]  = fmaf(p, v1.w, o[7]);
    o[8]  = fmaf(p, v2.x, o[8]);  o[9]  = fmaf(p, v2.y, o[9]);
    o[10] = fmaf(p, v2.z, o[10]); o[11] = fmaf(p, v2.w, o[11]);
    o[12] = fmaf(p, v3.x, o[12]); o[13] = fmaf(p, v3.y, o[13]);
    o[14] = fmaf(p, v3.z, o[14]); o[15] = fmaf(p, v3.w, o[15]);
}

// grid: B * (S/QR) blocks, 256 threads. thread -> (qrow = tid/4, 16-dim slice
// sub = tid%4). q and o live in registers; K/V tiles staged in LDS; score
// reads broadcast across the 16 lanes sharing a row.
__global__ __launch_bounds__(256) void flash_kernel(
    const float* __restrict__ Q, const float* __restrict__ K,
    const float* __restrict__ V, float* __restrict__ Out)
{
    __shared__ float ks[KT * HH];
    __shared__ float vs[KT * HH];
    const int tid = threadIdx.x;
    const int qrow = tid >> 2;
    const int sub16 = (tid & 3) * 16;
    const int batch = blockIdx.x >> 6;          // S/QR = 64 tiles per batch
    const int qtile = blockIdx.x & 63;
    const long qg = (long)batch * SS + qtile * QR + qrow;

    const float* qp = Q + qg * HH + sub16;
    const float4 q0 = ((const float4*)qp)[0];
    const float4 q1 = ((const float4*)qp)[1];
    const float4 q2 = ((const float4*)qp)[2];
    const float4 q3 = ((const float4*)qp)[3];

    float o[16];
#pragma unroll
    for (int d = 0; d < 16; ++d) o[d] = 0.f;
    float m = -1e30f, l = 0.f;

    const float4* Kb = (const float4*)(K + (long)batch * SS * HH);
    const float4* Vb = (const float4*)(V + (long)batch * SS * HH);
    float4* ks4 = (float4*)ks;
    float4* vs4 = (float4*)vs;

    for (int k0 = 0; k0 < SS; k0 += KT) {
        __syncthreads();
        const int base = k0 * (HH / 4);
        ks4[tid]       = Kb[base + tid];
        ks4[tid + 256] = Kb[base + tid + 256];
        vs4[tid]       = Vb[base + tid];
        vs4[tid + 256] = Vb[base + tid + 256];
        __syncthreads();

        float s[KT];
#pragma unroll
        for (int j = 0; j < KT; ++j)
            s[j] = dot16(q0, q1, q2, q3, ks + j * HH + sub16);
        // complete the 64-dim dot across the 4 lanes sharing this q row
#pragma unroll
        for (int j = 0; j < KT; ++j) {
            s[j] += __shfl_xor(s[j], 1);
            s[j] += __shfl_xor(s[j], 2);
        }
        float tm = s[0];
#pragma unroll
        for (int j = 1; j < KT; ++j) tm = fmaxf(tm, s[j]);
        const float mn = fmaxf(m, tm);
        const float scale = __expf(m - mn);
        l *= scale;
#pragma unroll
        for (int d = 0; d < 16; ++d) o[d] *= scale;
#pragma unroll
        for (int j = 0; j < KT; ++j) {
            const float p = __expf(s[j] - mn);
            l += p;
            s[j] = p;
        }
        m = mn;
#pragma unroll
        for (int j = 0; j < KT; ++j)
            pvacc(s[j], vs + j * HH + sub16, o);
    }

    const float inv = 1.0f / l;
    float* op = Out + qg * HH + sub16;
#pragma unroll
    for (int d4 = 0; d4 < 4; ++d4) {
        float4 r;
        r.x = o[d4 * 4 + 0] * inv;
        r.y = o[d4 * 4 + 1] * inv;
        r.z = o[d4 * 4 + 2] * inv;
        r.w = o[d4 * 4 + 3] * inv;
        ((float4*)op)[d4] = r;
    }
}

extern "C" void kernel_launch(void* const* d_in, const int* in_sizes, int n_in,
                              void* d_out, int out_size, void* d_ws, size_t ws_size,
                              hipStream_t stream) {
    const float* x  = (const float*)d_in[0];
    const float* Wq = (const float*)d_in[1];
    const float* bq = (const float*)d_in[2];
    const float* Wk = (const float*)d_in[3];
    const float* bk = (const float*)d_in[4];
    const float* Wv = (const float*)d_in[5];
    const float* bv = (const float*)d_in[6];
    float* out = (float*)d_out;

    // workspace: Q | K | V, each B*S*H fp32 (25.2 MB total)
    float* Q = (float*)d_ws;
    float* K = Q + (size_t)BB * SS * HH;
    float* V = K + (size_t)BB * SS * HH;

    qkv_proj_kernel<<<BB * SS / 64, 192, 0, stream>>>(x, Wq, bq, Wk, bk, Wv, bv,
                                                      Q, K, V);
    flash_kernel<<<BB * (SS / QR), 256, 0, stream>>>(Q, K, V, out);
}

// Round 2
// 236.961 us; speedup vs baseline: 4.3158x; 4.3158x over previous
//
#include <hip/hip_runtime.h>
#include <hip/hip_bf16.h>
#include <math.h>

#define BB 8
#define SS 4096
#define EE 128
#define HH 64

typedef __attribute__((ext_vector_type(8))) short short8;
typedef __attribute__((ext_vector_type(4))) float f32x4;

__device__ __forceinline__ short f2bf(float v) {
    __hip_bfloat16 h = __float2bfloat16(v);
    return __builtin_bit_cast(short, h);
}
__device__ __forceinline__ float bf2f(short s) {
    unsigned int u = ((unsigned int)(unsigned short)s) << 16;
    return __builtin_bit_cast(float, u);
}

// ---------------- QKV projection ----------------
// grid: B*S/64 blocks, 192 threads. Block = 64 rows of x staged in LDS.
// Thread t owns one output column of {Q,K,V} (which = t/64) for all 64 rows.
// Emits: Q fp32 [b][s][h]; Khi/Klo bf16-split [b][key][h]; Vt bf16 TRANSPOSED [b][o][key].
__global__ __launch_bounds__(192) void qkv_proj_kernel(
    const float* __restrict__ x,
    const float* __restrict__ Wq, const float* __restrict__ bq,
    const float* __restrict__ Wk, const float* __restrict__ bk,
    const float* __restrict__ Wv, const float* __restrict__ bv,
    float* __restrict__ Q, short* __restrict__ Khi,
    short* __restrict__ Klo, short* __restrict__ Vt)
{
    __shared__ float xs[64 * EE];
    const int tid = threadIdx.x;
    const long rowbase = (long)blockIdx.x * 64;

    const float4* xg = (const float4*)(x + rowbase * EE);
    float4* xs4 = (float4*)xs;
    for (int i = tid; i < 64 * EE / 4; i += 192) xs4[i] = xg[i];
    __syncthreads();

    const int col = tid & 63;
    const int which = tid >> 6;                 // wave-uniform (192 = 3 waves)
    const float* W    = (which == 0) ? Wq : (which == 1) ? Wk : Wv;
    const float* bias = (which == 0) ? bq : (which == 1) ? bk : bv;

    float acc[64];
    const float b = bias[col];
#pragma unroll
    for (int r = 0; r < 64; ++r) acc[r] = b;

    for (int e = 0; e < EE; e += 4) {
        const float w0 = W[(e + 0) * HH + col];
        const float w1 = W[(e + 1) * HH + col];
        const float w2 = W[(e + 2) * HH + col];
        const float w3 = W[(e + 3) * HH + col];
#pragma unroll
        for (int r = 0; r < 64; ++r) {
            const float4 xv = *(const float4*)(xs + r * EE + e);
            float a = acc[r];
            a = fmaf(w0, xv.x, a);
            a = fmaf(w1, xv.y, a);
            a = fmaf(w2, xv.z, a);
            a = fmaf(w3, xv.w, a);
            acc[r] = a;
        }
    }

    if (which == 0) {
#pragma unroll
        for (int r = 0; r < 64; ++r) Q[(rowbase + r) * HH + col] = acc[r];
    } else if (which == 1) {
#pragma unroll
        for (int r = 0; r < 64; ++r) {
            const float v = acc[r];
            const short h = f2bf(v);
            Khi[(rowbase + r) * HH + col] = h;
            Klo[(rowbase + r) * HH + col] = f2bf(v - bf2f(h));
        }
    } else {
        const long batch = rowbase >> 12;       // /SS
        const long key0  = rowbase & 4095;
        short* vtb = Vt + batch * (long)SS * HH + (long)col * SS + key0;
#pragma unroll
        for (int r = 0; r < 64; ++r) vtb[r] = f2bf(acc[r]);
    }
}

// ---------------- MFMA flash attention ----------------
// 512 blocks x 256 threads (4 waves). Wave = 16 q rows; KV tile = 64 keys.
// Swapped QK^T: S^T = mfma(A=K_tile, B=Q) so C-layout col = q = lane&15 ->
// softmax row-reduce is in-lane tree + shfl_xor(16,32). P goes through a
// wave-private LDS tile to become the A operand of O = mfma(P, V).
// All LDS tiles use the G4 XOR swizzle (byte ^= (row&7)<<4).
__global__ __launch_bounds__(256) void flash_kernel(
    const float* __restrict__ Q, const short* __restrict__ Khi,
    const short* __restrict__ Klo, const short* __restrict__ Vt,
    float* __restrict__ Out)
{
    __shared__ __align__(16) short khi_s[64 * HH];
    __shared__ __align__(16) short klo_s[64 * HH];
    __shared__ __align__(16) short vt_s[64 * HH];
    __shared__ __align__(16) short p_s[4 * 16 * HH];

    const int tid  = threadIdx.x;
    const int lane = tid & 63;
    const int wid  = tid >> 6;
    const int ln15 = lane & 15;
    const int lg   = lane >> 4;                 // 0..3
    const int batch = blockIdx.x & 7;           // XCD-affine: batch -> one XCD's L2
    const int qtile = blockIdx.x >> 3;

    // hoisted Q fragments (hi/lo split), B-operand layout:
    // lane holds col q = ln15, k-slots h = 8*lg + j (+32*s)
    short8 qh[2], ql[2];
    {
        const long qrow = (long)batch * SS + qtile * 64 + wid * 16 + ln15;
        const float* qp = Q + qrow * HH + lg * 8;
#pragma unroll
        for (int s = 0; s < 2; ++s) {
            float qf[8];
            *(float4*)(&qf[0]) = *(const float4*)(qp + s * 32);
            *(float4*)(&qf[4]) = *(const float4*)(qp + s * 32 + 4);
#pragma unroll
            for (int j = 0; j < 8; ++j) {
                const short h = f2bf(qf[j]);
                qh[s][j] = h;
                ql[s][j] = f2bf(qf[j] - bf2f(h));
            }
        }
    }

    f32x4 oacc[4];
#pragma unroll
    for (int ot = 0; ot < 4; ++ot) oacc[ot] = (f32x4){0.f, 0.f, 0.f, 0.f};
    float m = -1e30f, l = 0.f;

    short* pw = p_s + wid * (16 * HH);          // wave-private P tile (2 KB)
    const int swq = (ln15 & 7) << 4;

    for (int k0 = 0; k0 < SS; k0 += 64) {
        __syncthreads();
        {
            const uint4* skh = (const uint4*)(Khi + ((long)batch * SS + k0) * HH);
            const uint4* skl = (const uint4*)(Klo + ((long)batch * SS + k0) * HH);
            const short* vbase = Vt + (long)batch * SS * HH + k0;
#pragma unroll
            for (int c = 0; c < 2; ++c) {
                const int ch  = tid + c * 256;
                const int row = ch >> 3;        // 8 x 16B chunks per 128B row
                const int cc  = ch & 7;
                const int dst = (row * 128 + cc * 16) ^ ((row & 7) << 4);
                *(uint4*)((char*)khi_s + dst) = skh[ch];
                *(uint4*)((char*)klo_s + dst) = skl[ch];
                *(uint4*)((char*)vt_s  + dst) = ((const uint4*)(vbase + (long)row * SS))[cc];
            }
        }
        __syncthreads();

        // S^T tiles: 4 key-tiles x (2 k-steps x 3 split terms)
        f32x4 sacc[4];
#pragma unroll
        for (int kt = 0; kt < 4; ++kt) {
            f32x4 acc = (f32x4){0.f, 0.f, 0.f, 0.f};
            const int key = kt * 16 + ln15;     // A row = lane&15
            const int rb  = key * 128;
            const int swz = (key & 7) << 4;
#pragma unroll
            for (int s = 0; s < 2; ++s) {
                const int off = (rb + lg * 16 + s * 64) ^ swz;
                const short8 ah = *(const short8*)((const char*)khi_s + off);
                const short8 al = *(const short8*)((const char*)klo_s + off);
                acc = __builtin_amdgcn_mfma_f32_16x16x32_bf16(ah, qh[s], acc, 0, 0, 0);
                acc = __builtin_amdgcn_mfma_f32_16x16x32_bf16(ah, ql[s], acc, 0, 0, 0);
                acc = __builtin_amdgcn_mfma_f32_16x16x32_bf16(al, qh[s], acc, 0, 0, 0);
            }
            sacc[kt] = acc;
        }

        // online softmax for q-row = ln15 (lane holds keys 16*kt + 4*lg + r)
        float t0 = fmaxf(fmaxf(sacc[0][0], sacc[0][1]), fmaxf(sacc[0][2], sacc[0][3]));
        float t1 = fmaxf(fmaxf(sacc[1][0], sacc[1][1]), fmaxf(sacc[1][2], sacc[1][3]));
        float t2 = fmaxf(fmaxf(sacc[2][0], sacc[2][1]), fmaxf(sacc[2][2], sacc[2][3]));
        float t3 = fmaxf(fmaxf(sacc[3][0], sacc[3][1]), fmaxf(sacc[3][2], sacc[3][3]));
        float tm = fmaxf(fmaxf(t0, t1), fmaxf(t2, t3));
        tm = fmaxf(tm, __shfl_xor(tm, 16));
        tm = fmaxf(tm, __shfl_xor(tm, 32));
        const float mn = fmaxf(m, tm);
        const float alpha = __expf(m - mn);

        float p[4][4];
#pragma unroll
        for (int kt = 0; kt < 4; ++kt)
#pragma unroll
            for (int r = 0; r < 4; ++r)
                p[kt][r] = __expf(sacc[kt][r] - mn);
        float ps = ((p[0][0] + p[0][1]) + (p[0][2] + p[0][3]))
                 + ((p[1][0] + p[1][1]) + (p[1][2] + p[1][3]))
                 + ((p[2][0] + p[2][1]) + (p[2][2] + p[2][3]))
                 + ((p[3][0] + p[3][1]) + (p[3][2] + p[3][3]));
        ps += __shfl_xor(ps, 16);
        ps += __shfl_xor(ps, 32);
        l = l * alpha + ps;
        m = mn;

        // rescale O accumulators (O rows are q = 4*lg + r -> fetch that row's alpha)
#pragma unroll
        for (int r = 0; r < 4; ++r) {
            const float ar = __shfl(alpha, lg * 4 + r);
            oacc[0][r] *= ar; oacc[1][r] *= ar;
            oacc[2][r] *= ar; oacc[3][r] *= ar;
        }

        // P -> LDS (bf16, packed pairs), row q = ln15, key = 16*kt + 4*lg + r
#pragma unroll
        for (int kt = 0; kt < 4; ++kt)
#pragma unroll
            for (int rp = 0; rp < 2; ++rp) {
                const unsigned int pk =
                    (unsigned int)(unsigned short)f2bf(p[kt][2 * rp]) |
                    ((unsigned int)(unsigned short)f2bf(p[kt][2 * rp + 1]) << 16);
                const int key = kt * 16 + lg * 4 + rp * 2;
                const int off = (ln15 * 128 + key * 2) ^ swq;
                *(unsigned int*)((char*)pw + off) = pk;
            }

        // O += P . V   (A = P[q][key], B = V[key][o] read from Vt[o][key])
#pragma unroll
        for (int s = 0; s < 2; ++s) {
            const int poff = (ln15 * 128 + lg * 16 + s * 64) ^ swq;
            const short8 pa = *(const short8*)((const char*)pw + poff);
#pragma unroll
            for (int ot = 0; ot < 4; ++ot) {
                const int o = ot * 16 + ln15;   // B col = lane&15
                const int voff = (o * 128 + lg * 16 + s * 64) ^ ((o & 7) << 4);
                const short8 vb = *(const short8*)((const char*)vt_s + voff);
                oacc[ot] = __builtin_amdgcn_mfma_f32_16x16x32_bf16(pa, vb, oacc[ot], 0, 0, 0);
            }
        }
    }

    // epilogue: divide by l (row q = 4*lg + r) and store
    const float linv = 1.0f / l;
#pragma unroll
    for (int r = 0; r < 4; ++r) {
        const float ir = __shfl(linv, lg * 4 + r);
        const long row = (long)batch * SS + qtile * 64 + wid * 16 + lg * 4 + r;
        float* op = Out + row * HH + ln15;
        op[0]  = oacc[0][r] * ir;
        op[16] = oacc[1][r] * ir;
        op[32] = oacc[2][r] * ir;
        op[48] = oacc[3][r] * ir;
    }
}

extern "C" void kernel_launch(void* const* d_in, const int* in_sizes, int n_in,
                              void* d_out, int out_size, void* d_ws, size_t ws_size,
                              hipStream_t stream) {
    const float* x  = (const float*)d_in[0];
    const float* Wq = (const float*)d_in[1];
    const float* bq = (const float*)d_in[2];
    const float* Wk = (const float*)d_in[3];
    const float* bk = (const float*)d_in[4];
    const float* Wv = (const float*)d_in[5];
    const float* bv = (const float*)d_in[6];
    float* out = (float*)d_out;

    // workspace: Q fp32 (8 MB) | Khi bf16 (4 MB) | Klo bf16 (4 MB) | Vt bf16 (4 MB)
    float* Q   = (float*)d_ws;
    short* Khi = (short*)(Q + (size_t)BB * SS * HH);
    short* Klo = Khi + (size_t)BB * SS * HH;
    short* Vt  = Klo + (size_t)BB * SS * HH;

    qkv_proj_kernel<<<BB * SS / 64, 192, 0, stream>>>(x, Wq, bq, Wk, bk, Wv, bv,
                                                      Q, Khi, Klo, Vt);
    flash_kernel<<<BB * (SS / 64), 256, 0, stream>>>(Q, Khi, Klo, Vt, out);
}

// Round 3
// 93.593 us; speedup vs baseline: 10.9267x; 2.5318x over previous
//
#include <hip/hip_runtime.h>
#include <math.h>

#define BB 8
#define SS 4096
#define EE 128
#define HH 64

typedef _Float16 f16;
typedef __attribute__((ext_vector_type(8))) _Float16 f16x8;
typedef __attribute__((ext_vector_type(4))) float f32x4;

__device__ __forceinline__ unsigned short f2h(float v) {
    f16 h = (f16)v;
    return __builtin_bit_cast(unsigned short, h);
}

// ---------------- W transpose+convert setup ----------------
// Wt f16 [192 cols][128 e]: cols 0-63 = Wq, 64-127 = Wk, 128-191 = Wv.
__global__ __launch_bounds__(256) void wtrans_kernel(
    const float* __restrict__ Wq, const float* __restrict__ Wk,
    const float* __restrict__ Wv, f16* __restrict__ Wt)
{
    const int idx = blockIdx.x * 256 + threadIdx.x;
    if (idx >= 192 * 128) return;
    const int col = idx >> 7, e = idx & 127;
    const float v = (col < 64)  ? Wq[e * 64 + col]
                  : (col < 128) ? Wk[e * 64 + (col - 64)]
                                : Wv[e * 64 + (col - 128)];
    Wt[col * 128 + e] = (f16)v;
}

// ---------------- QKV projection: fp16 MFMA GEMM ----------------
// 512 blocks x 256 thr (4 waves). Block = 64 rows of x; wave = 16 rows x 192 cols.
// A = x rows (LDS, fp16, XOR-swizzled); B = Wt from global (L2-hot, 48 KB).
// Emits Q f16 [b][s][h], K f16 [b][key][h], Vt f16 TRANSPOSED [b][o][key].
__global__ __launch_bounds__(256) void qkv_kernel(
    const float* __restrict__ x, const f16* __restrict__ Wt,
    const float* __restrict__ bq, const float* __restrict__ bk,
    const float* __restrict__ bv,
    f16* __restrict__ Q, f16* __restrict__ K, f16* __restrict__ Vt)
{
    __shared__ __align__(16) short xs[64 * EE];   // fp16 tile, 256 B rows
    const int tid = threadIdx.x;
    const long rowbase = (long)blockIdx.x * 64;

    // stage x (fp32 -> fp16), 32 elems/thread
    {
        const float4* xg = (const float4*)(x + rowbase * EE);
#pragma unroll
        for (int j = 0; j < 8; ++j) {
            const int eidx = tid * 32 + j * 4;          // element index in tile
            const float4 v = xg[eidx >> 2];
            unsigned long long pk =
                (unsigned long long)f2h(v.x) |
                ((unsigned long long)f2h(v.y) << 16) |
                ((unsigned long long)f2h(v.z) << 32) |
                ((unsigned long long)f2h(v.w) << 48);
            const int row = eidx >> 7;
            const int off = (row * 256 + (eidx & 127) * 2) ^ ((row & 7) << 4);
            *(unsigned long long*)((char*)xs + off) = pk;
        }
    }
    __syncthreads();

    const int lane = tid & 63;
    const int wid  = tid >> 6;
    const int ln15 = lane & 15;
    const int lg   = lane >> 4;

    // A fragments: row = wid*16 + ln15, k = s*32 + lg*8 + j
    f16x8 xa[4];
    {
        const int row = wid * 16 + ln15;
        const int swz = (row & 7) << 4;
#pragma unroll
        for (int s = 0; s < 4; ++s) {
            const int off = (row * 256 + lg * 16 + s * 64) ^ swz;
            xa[s] = *(const f16x8*)((const char*)xs + off);
        }
    }

    f32x4 acc[12];
#pragma unroll
    for (int ct = 0; ct < 12; ++ct) acc[ct] = (f32x4){0.f, 0.f, 0.f, 0.f};

#pragma unroll
    for (int ct = 0; ct < 12; ++ct) {
        const f16* wtp = Wt + (ct * 16 + ln15) * 128 + lg * 8;
#pragma unroll
        for (int s = 0; s < 4; ++s) {
            const f16x8 wb = *(const f16x8*)(wtp + s * 32);
            acc[ct] = __builtin_amdgcn_mfma_f32_16x16x32_f16(xa[s], wb, acc[ct], 0, 0, 0);
        }
    }

    // epilogue: C row = 4*lg + r (local to wave tile), col = ct*16 + ln15
    const long grow0 = rowbase + wid * 16 + 4 * lg;
#pragma unroll
    for (int ct = 0; ct < 4; ++ct) {
        const int col = ct * 16 + ln15;
        const float b = bq[col];
#pragma unroll
        for (int r = 0; r < 4; ++r)
            Q[(grow0 + r) * HH + col] = (f16)(acc[ct][r] + b);
    }
#pragma unroll
    for (int ct = 4; ct < 8; ++ct) {
        const int col = (ct - 4) * 16 + ln15;
        const float b = bk[col];
#pragma unroll
        for (int r = 0; r < 4; ++r)
            K[(grow0 + r) * HH + col] = (f16)(acc[ct][r] + b);
    }
    {
        const long batch = rowbase >> 12;
        const long inrow = (rowbase & 4095) + wid * 16 + 4 * lg;
#pragma unroll
        for (int ct = 8; ct < 12; ++ct) {
            const int o = (ct - 8) * 16 + ln15;
            const float b = bv[o];
            unsigned long long pk =
                (unsigned long long)f2h(acc[ct][0] + b) |
                ((unsigned long long)f2h(acc[ct][1] + b) << 16) |
                ((unsigned long long)f2h(acc[ct][2] + b) << 32) |
                ((unsigned long long)f2h(acc[ct][3] + b) << 48);
            *(unsigned long long*)(Vt + ((long)batch * HH + o) * SS + inrow) = pk;
        }
    }
}

// ---------------- MFMA flash attention, fp16, split-K2 ----------------
// grid 1024 = 8 batch (XCD-affine, &7) x 2 split x 64 qtile; 4 waves.
// Wave = 16 q rows. KV tile = 64 keys. T14 async stage (global->reg early,
// ds_write late). T13 defer-max (threshold 8). Partials: raw O + (m,l).
__global__ __launch_bounds__(256, 4) void flash_kernel(
    const f16* __restrict__ Q, const f16* __restrict__ K,
    const f16* __restrict__ Vt, float* __restrict__ Opart,
    float* __restrict__ ml)
{
    __shared__ __align__(16) short k_s[64 * HH];      // 8 KB
    __shared__ __align__(16) short v_s[64 * HH];      // 8 KB  [o][key]
    __shared__ __align__(16) short p_s[4 * 16 * HH];  // 8 KB  per-wave P

    const int tid  = threadIdx.x;
    const int lane = tid & 63;
    const int wid  = tid >> 6;
    const int ln15 = lane & 15;
    const int lg   = lane >> 4;
    const int batch = blockIdx.x & 7;
    const int rest  = blockIdx.x >> 3;
    const int split = rest & 1;
    const int qtile = rest >> 1;
    const int k0base = split * (SS / 2);

    // Q fragments (B-operand): col q = ln15, k = s*32 + lg*8 + j
    f16x8 qf[2];
    {
        const long qrow = (long)batch * SS + qtile * 64 + wid * 16 + ln15;
        const f16* qp = Q + qrow * HH + lg * 8;
        qf[0] = *(const f16x8*)(qp);
        qf[1] = *(const f16x8*)(qp + 32);
    }

    f32x4 oacc[4];
#pragma unroll
    for (int ot = 0; ot < 4; ++ot) oacc[ot] = (f32x4){0.f, 0.f, 0.f, 0.f};
    float m = -1e30f, l = 0.f;

    short* pw = p_s + wid * (16 * HH);
    const int swq = (ln15 & 7) << 4;

    // staging: 512 16B-chunks per 8KB tile, 2 per thread per array
    const int srow = tid >> 3;            // chunk row (key for K, o for V)
    const int scc  = tid & 7;
    const int d0 = (srow * 128 + scc * 16) ^ ((srow & 7) << 4);
    const int d1 = ((srow + 32) * 128 + scc * 16) ^ (((srow + 32) & 7) << 4);

    uint4 kr0, kr1, vr0, vr1;
    {   // prologue: tile 0
        const uint4* kb = (const uint4*)(K + ((long)batch * SS + k0base) * HH);
        kr0 = kb[tid]; kr1 = kb[tid + 256];
        const f16* vb = Vt + (long)batch * HH * SS + k0base;
        vr0 = *(const uint4*)(vb + (long)srow * SS + scc * 8);
        vr1 = *(const uint4*)(vb + (long)(srow + 32) * SS + scc * 8);
        *(uint4*)((char*)k_s + d0) = kr0;
        *(uint4*)((char*)k_s + d1) = kr1;
        *(uint4*)((char*)v_s + d0) = vr0;
        *(uint4*)((char*)v_s + d1) = vr1;
    }
    __syncthreads();

    for (int t = 0; t < 32; ++t) {
        // T14: issue next tile's global loads now, write after barrier
        if (t + 1 < 32) {
            const int k0 = k0base + (t + 1) * 64;
            const uint4* kb = (const uint4*)(K + ((long)batch * SS + k0) * HH);
            kr0 = kb[tid]; kr1 = kb[tid + 256];
            const f16* vb = Vt + (long)batch * HH * SS + k0;
            vr0 = *(const uint4*)(vb + (long)srow * SS + scc * 8);
            vr1 = *(const uint4*)(vb + (long)(srow + 32) * SS + scc * 8);
        }

        // ---- QK^T (swapped: A = K rows, B = Q) ----
        f32x4 sacc[4];
#pragma unroll
        for (int kt = 0; kt < 4; ++kt) {
            f32x4 a = (f32x4){0.f, 0.f, 0.f, 0.f};
            const int key = kt * 16 + ln15;
            const int rb = key * 128, swz = (key & 7) << 4;
#pragma unroll
            for (int s = 0; s < 2; ++s) {
                const f16x8 ka = *(const f16x8*)((const char*)k_s + ((rb + lg * 16 + s * 64) ^ swz));
                a = __builtin_amdgcn_mfma_f32_16x16x32_f16(ka, qf[s], a, 0, 0, 0);
            }
            sacc[kt] = a;
        }

        // ---- online softmax, per q-row = ln15, defer-max thr=8 ----
        float tm = sacc[0][0];
#pragma unroll
        for (int kt = 0; kt < 4; ++kt)
#pragma unroll
            for (int r = 0; r < 4; ++r) tm = fmaxf(tm, sacc[kt][r]);
        tm = fmaxf(tm, __shfl_xor(tm, 16));
        tm = fmaxf(tm, __shfl_xor(tm, 32));
        if (!__all(tm <= m + 8.0f)) {
            const float mn = fmaxf(m, tm);
            const float alpha = __expf(m - mn);
            l *= alpha;
#pragma unroll
            for (int r = 0; r < 4; ++r) {
                const float ar = __shfl(alpha, lg * 4 + r);
                oacc[0][r] *= ar; oacc[1][r] *= ar;
                oacc[2][r] *= ar; oacc[3][r] *= ar;
            }
            m = mn;
        }

        float p[16];
#pragma unroll
        for (int kt = 0; kt < 4; ++kt)
#pragma unroll
            for (int r = 0; r < 4; ++r)
                p[kt * 4 + r] = __expf(sacc[kt][r] - m);
        float ps = 0.f;
#pragma unroll
        for (int j = 0; j < 16; ++j) ps += p[j];
        ps += __shfl_xor(ps, 16);
        ps += __shfl_xor(ps, 32);
        l += ps;

        // P -> wave-private LDS (fp16 pairs): row q = ln15, key = 16kt + 4lg + 2rp
#pragma unroll
        for (int kt = 0; kt < 4; ++kt)
#pragma unroll
            for (int rp = 0; rp < 2; ++rp) {
                const unsigned int pk =
                    (unsigned int)f2h(p[kt * 4 + 2 * rp]) |
                    ((unsigned int)f2h(p[kt * 4 + 2 * rp + 1]) << 16);
                const int key = kt * 16 + lg * 4 + rp * 2;
                *(unsigned int*)((char*)pw + ((ln15 * 128 + key * 2) ^ swq)) = pk;
            }

        // ---- O += P.V ----
#pragma unroll
        for (int s = 0; s < 2; ++s) {
            const f16x8 pa = *(const f16x8*)((const char*)pw + ((ln15 * 128 + lg * 16 + s * 64) ^ swq));
#pragma unroll
            for (int ot = 0; ot < 4; ++ot) {
                const int o = ot * 16 + ln15;
                const f16x8 vb = *(const f16x8*)((const char*)v_s + ((o * 128 + lg * 16 + s * 64) ^ ((o & 7) << 4)));
                oacc[ot] = __builtin_amdgcn_mfma_f32_16x16x32_f16(pa, vb, oacc[ot], 0, 0, 0);
            }
        }

        __syncthreads();                 // all waves done reading tile t
        if (t + 1 < 32) {
            *(uint4*)((char*)k_s + d0) = kr0;
            *(uint4*)((char*)k_s + d1) = kr1;
            *(uint4*)((char*)v_s + d0) = vr0;
            *(uint4*)((char*)v_s + d1) = vr1;
        }
        __syncthreads();                 // tile t+1 visible
    }

    // epilogue: raw partials + (m,l)
    const long ridx = (long)batch * SS + qtile * 64 + wid * 16;
#pragma unroll
    for (int r = 0; r < 4; ++r) {
        float* op = Opart + ((long)split * (BB * SS) + ridx + lg * 4 + r) * HH + ln15;
        op[0]  = oacc[0][r];
        op[16] = oacc[1][r];
        op[32] = oacc[2][r];
        op[48] = oacc[3][r];
    }
    if (lg == 0) {
        float* mlp = ml + ((long)split * (BB * SS) + ridx + ln15) * 2;
        mlp[0] = m;
        mlp[1] = l;
    }
}

// ---------------- split-K merge ----------------
__global__ __launch_bounds__(256) void merge_kernel(
    const float* __restrict__ Opart, const float* __restrict__ ml,
    float* __restrict__ Out)
{
    const int gid = blockIdx.x * 256 + threadIdx.x;   // 131072
    const long row = gid >> 2;
    const int c0 = (gid & 3) * 16;
    const float m0 = ml[row * 2], l0 = ml[row * 2 + 1];
    const float m1 = ml[(BB * SS + row) * 2], l1 = ml[(BB * SS + row) * 2 + 1];
    const float M = fmaxf(m0, m1);
    const float w0 = __expf(m0 - M), w1 = __expf(m1 - M);
    const float inv = 1.0f / (w0 * l0 + w1 * l1);
    const float4* o0 = (const float4*)(Opart + row * HH + c0);
    const float4* o1 = (const float4*)(Opart + ((long)BB * SS + row) * HH + c0);
    float4* dst = (float4*)(Out + row * HH + c0);
#pragma unroll
    for (int i = 0; i < 4; ++i) {
        const float4 a = o0[i], b = o1[i];
        float4 r;
        r.x = (w0 * a.x + w1 * b.x) * inv;
        r.y = (w0 * a.y + w1 * b.y) * inv;
        r.z = (w0 * a.z + w1 * b.z) * inv;
        r.w = (w0 * a.w + w1 * b.w) * inv;
        dst[i] = r;
    }
}

extern "C" void kernel_launch(void* const* d_in, const int* in_sizes, int n_in,
                              void* d_out, int out_size, void* d_ws, size_t ws_size,
                              hipStream_t stream) {
    const float* x  = (const float*)d_in[0];
    const float* Wq = (const float*)d_in[1];
    const float* bq = (const float*)d_in[2];
    const float* Wk = (const float*)d_in[3];
    const float* bk = (const float*)d_in[4];
    const float* Wv = (const float*)d_in[5];
    const float* bv = (const float*)d_in[6];
    float* out = (float*)d_out;

    // ws: Q f16 4MB | K f16 4MB | Vt f16 4MB | Wt f16 48KB | Opart f32 16MB | ml f32 512KB
    const size_t NTOK = (size_t)BB * SS;
    f16* Q  = (f16*)d_ws;
    f16* K  = Q + NTOK * HH;
    f16* Vt = K + NTOK * HH;
    f16* Wt = Vt + NTOK * HH;
    float* Opart = (float*)(Wt + 192 * 128);
    float* ml = Opart + 2 * NTOK * HH;

    wtrans_kernel<<<96, 256, 0, stream>>>(Wq, Wk, Wv, Wt);
    qkv_kernel<<<BB * SS / 64, 256, 0, stream>>>(x, Wt, bq, bk, bv, Q, K, Vt);
    flash_kernel<<<BB * 2 * (SS / 64), 256, 0, stream>>>(Q, K, Vt, Opart, ml);
    merge_kernel<<<BB * SS * 4 / 256, 256, 0, stream>>>(Opart, ml, out);
}